// Round 3
// baseline (491.056 us; speedup 1.0000x reference)
//
#include <hip/hip_runtime.h>

#define F_IN 128
#define F_OUT 32

// ---------------- K0: spectral norm, write W/sigma to ws ----------------
__global__ void k0_specnorm(const float* __restrict__ W, const float* __restrict__ u,
                            float* __restrict__ Wsc) {
    __shared__ float v[F_IN];
    __shared__ float red[F_IN];
    __shared__ float scal;
    int t = threadIdx.x;  // 0..127
    float acc = 0.f;
    for (int i = 0; i < F_OUT; ++i) acc += W[i * F_IN + t] * u[i];
    v[t] = acc;
    red[t] = acc * acc;
    __syncthreads();
    if (t == 0) {
        float s = 0.f;
        for (int i = 0; i < F_IN; ++i) s += red[i];
        scal = 1.0f / fmaxf(sqrtf(s), 1e-12f);
    }
    __syncthreads();
    v[t] = v[t] * scal;
    __syncthreads();
    if (t < F_OUT) {
        float a2 = 0.f;
        for (int j = 0; j < F_IN; ++j) a2 += W[t * F_IN + j] * v[j];
        red[t] = a2 * a2;
    }
    __syncthreads();
    if (t == 0) {
        float s = 0.f;
        for (int i = 0; i < F_OUT; ++i) s += red[i];
        scal = 1.0f / fmaxf(sqrtf(s), 1e-30f);  // 1/sigma
    }
    __syncthreads();
    float is = scal;
    for (int i = 0; i < F_OUT; ++i)
        Wsc[i * F_IN + t] = W[i * F_IN + t] * is;
}

// ---------------- K1: xws = (x @ Wsc^T) * dis[row], LDS-tiled -----------
__global__ __launch_bounds__(256) void k1_xw(const float* __restrict__ x,
                                             const float* __restrict__ Wsc,
                                             const float* __restrict__ dis,
                                             float* __restrict__ xw, int Nn) {
    __shared__ float xs[128 * 65];   // [r][kk], stride 65
    __shared__ float wt[128 * 32];   // [k][f], stride 32
    int t = threadIdx.x;
    int rbase = blockIdx.x * 128;

    {   // stage W transposed
        int f = t >> 3;
        int kb = 16 * (t & 7);
        const float4* wrow = (const float4*)(Wsc + (size_t)f * F_IN + kb);
#pragma unroll
        for (int j = 0; j < 4; ++j) {
            float4 w = wrow[j];
            int k = kb + 4 * j;
            wt[(k + 0) * 32 + f] = w.x;
            wt[(k + 1) * 32 + f] = w.y;
            wt[(k + 2) * 32 + f] = w.z;
            wt[(k + 3) * 32 + f] = w.w;
        }
    }

    int r0 = (t >> 3) * 4;   // 0..124
    int f0 = (t & 7) * 4;    // 0..28
    float4 acc0 = {0, 0, 0, 0}, acc1 = {0, 0, 0, 0};
    float4 acc2 = {0, 0, 0, 0}, acc3 = {0, 0, 0, 0};

    const float4* wt4 = (const float4*)wt;
    int fq = f0 >> 2;

    for (int kc = 0; kc < 2; ++kc) {
        __syncthreads();
        {   // stage x chunk: 128 rows x 64 cols
            int rr = t >> 4;
            int k0 = 4 * (t & 15);
#pragma unroll
            for (int p = 0; p < 8; ++p) {
                int r = p * 16 + rr;
                int grow = rbase + r;
                if (grow >= Nn) grow = Nn - 1;
                float4 v = *(const float4*)(x + (size_t)grow * F_IN + kc * 64 + k0);
                xs[r * 65 + k0 + 0] = v.x;
                xs[r * 65 + k0 + 1] = v.y;
                xs[r * 65 + k0 + 2] = v.z;
                xs[r * 65 + k0 + 3] = v.w;
            }
        }
        __syncthreads();
#pragma unroll 4
        for (int kk = 0; kk < 64; ++kk) {
            int k = kc * 64 + kk;
            float4 w = wt4[k * 8 + fq];
            float x0 = xs[(r0 + 0) * 65 + kk];
            float x1 = xs[(r0 + 1) * 65 + kk];
            float x2 = xs[(r0 + 2) * 65 + kk];
            float x3 = xs[(r0 + 3) * 65 + kk];
            acc0.x += x0 * w.x; acc0.y += x0 * w.y; acc0.z += x0 * w.z; acc0.w += x0 * w.w;
            acc1.x += x1 * w.x; acc1.y += x1 * w.y; acc1.z += x1 * w.z; acc1.w += x1 * w.w;
            acc2.x += x2 * w.x; acc2.y += x2 * w.y; acc2.z += x2 * w.z; acc2.w += x2 * w.w;
            acc3.x += x3 * w.x; acc3.y += x3 * w.y; acc3.z += x3 * w.z; acc3.w += x3 * w.w;
        }
    }
    int g0 = rbase + r0;
#pragma unroll
    for (int q = 0; q < 4; ++q) {
        int g = g0 + q;
        if (g < Nn) {
            float d = dis[g];
            float4 a = (q == 0) ? acc0 : (q == 1) ? acc1 : (q == 2) ? acc2 : acc3;
            a.x *= d; a.y *= d; a.z *= d; a.w *= d;
            *(float4*)(xw + (size_t)g * F_OUT + f0) = a;
        }
    }
}

// ------- K2: degree + per-(bucket, blockgroup) histogram (fused) ---------
// 2048 edges per block; g = blockIdx & 7 partitions staging frontiers.
__global__ void k2_hist(const int* __restrict__ col, int* __restrict__ deg,
                        int* __restrict__ cnt_bg, int E_) {
    int g = blockIdx.x & 7;
    int base = blockIdx.x * 2048 + threadIdx.x;
#pragma unroll
    for (int i = 0; i < 8; ++i) {
        int e = base + i * 256;
        if (e < E_) {
            int c = col[e];
            atomicAdd(&deg[c], 1);
            atomicAdd(&cnt_bg[(c >> 7) * 8 + g], 1);
        }
    }
}

// ---------------- K3: dis = rsqrt(deg + 1) ----------------
__global__ void k3_dis(const int* __restrict__ cnt, float* __restrict__ dis, int Nn) {
    int i = blockIdx.x * blockDim.x + threadIdx.x;
    if (i < Nn) dis[i] = rsqrtf((float)cnt[i] + 1.0f);
}

// ---------------- Node-degree scan (3 kernels) -> cursor[N+1] -------------
__global__ void k_s1(const int* __restrict__ cnt, int* __restrict__ bsum, int Nn) {
    __shared__ int sd[256];
    int t = threadIdx.x;
    int base = blockIdx.x * 1024 + 4 * t;
    int s = 0;
#pragma unroll
    for (int i = 0; i < 4; ++i) {
        int idx = base + i;
        s += (idx < Nn) ? cnt[idx] : 0;
    }
    sd[t] = s;
    __syncthreads();
    for (int o = 128; o > 0; o >>= 1) {
        if (t < o) sd[t] += sd[t + o];
        __syncthreads();
    }
    if (t == 0) bsum[blockIdx.x] = sd[0];
}

__global__ void k_s2(int* __restrict__ bsum, int nb, int* __restrict__ cursor, int Nn) {
    if (threadIdx.x == 0 && blockIdx.x == 0) {
        int run = 0;
        for (int i = 0; i < nb; ++i) { int v = bsum[i]; bsum[i] = run; run += v; }
        cursor[Nn] = run;  // == E
    }
}

__global__ void k_s3(const int* __restrict__ cnt, const int* __restrict__ boff,
                     int* __restrict__ cursor, int Nn) {
    __shared__ int sd[256];
    int t = threadIdx.x;
    int base = blockIdx.x * 1024 + 4 * t;
    int loc[4];
    int s = 0;
#pragma unroll
    for (int i = 0; i < 4; ++i) {
        int idx = base + i;
        loc[i] = (idx < Nn) ? cnt[idx] : 0;
        s += loc[i];
    }
    int tsum = s;
    sd[t] = tsum;
    __syncthreads();
    for (int o = 1; o < 256; o <<= 1) {
        int v = (t >= o) ? sd[t - o] : 0;
        __syncthreads();
        sd[t] += v;
        __syncthreads();
    }
    int excl = sd[t] - tsum + boff[blockIdx.x];
#pragma unroll
    for (int i = 0; i < 4; ++i) {
        int idx = base + i;
        if (idx < Nn) cursor[idx] = excl;
        excl += loc[i];
    }
}

// --------- Scan of cnt_bg[n] -> sgoff (pristine) + scur (mutable) --------
__global__ void k_sbg(const int* __restrict__ cnt_bg, int* __restrict__ sgoff,
                      int* __restrict__ scur, int n) {
    __shared__ int sd[256];
    int t = threadIdx.x;
    int C = (n + 255) >> 8;
    int base = t * C;
    int hi = min(base + C, n);
    int s = 0;
    for (int i = base; i < hi; ++i) s += cnt_bg[i];
    int tsum = s;
    sd[t] = tsum;
    __syncthreads();
    for (int o = 1; o < 256; o <<= 1) {
        int v = (t >= o) ? sd[t - o] : 0;
        __syncthreads();
        sd[t] += v;
        __syncthreads();
    }
    int run = sd[t] - tsum;
    for (int i = base; i < hi; ++i) {
        sgoff[i] = run;
        scur[i] = run;
        run += cnt_bg[i];
    }
    if (t == 255) sgoff[n] = sd[255];  // == E
}

// ---- Phase 1: scatter packed (row<<7 | col&127) to (bucket,g) frontier ---
__global__ void k_scat1(const int* __restrict__ ei, int* __restrict__ scur,
                        unsigned* __restrict__ staging, int E_) {
    int g = blockIdx.x & 7;
    int base = blockIdx.x * 2048 + threadIdx.x;
#pragma unroll
    for (int i = 0; i < 8; ++i) {
        int e = base + i * 256;
        if (e < E_) {
            int c = ei[E_ + e];
            int r = ei[e];
            int b = c >> 7;
            int p = atomicAdd(&scur[b * 8 + g], 1);
            staging[p] = ((unsigned)r << 7) | (unsigned)(c & 127);
        }
    }
}

// ---- Phase 2: per-bucket local sort via LDS cursors -> esr ---------------
__global__ void k_sort2(const unsigned* __restrict__ staging, const int* __restrict__ sgoff,
                        const int* __restrict__ cursor, int* __restrict__ esr, int Nn) {
    __shared__ int lcur[128];
    int b = blockIdx.x;
    int t = threadIdx.x;
    int nb0 = b << 7;
    int nc = min(128, Nn - nb0);
    if (t < 128) lcur[t] = (t < nc) ? cursor[nb0 + t] : 0;
    __syncthreads();
    int s0 = sgoff[b * 8], s1 = sgoff[b * 8 + 8];
    for (int j = s0 + t; j < s1; j += 256) {
        unsigned v = staging[j];
        int lc = v & 127;
        int p = atomicAdd(&lcur[lc], 1);
        esr[p] = (int)(v >> 7);
    }
}

// ---- K4g: per-node gather + epilogue (chunked shfl broadcast) ------------
__global__ void k4_gather(const int* __restrict__ esr, const int* __restrict__ cursor,
                          const float* __restrict__ xws, const float* __restrict__ dis,
                          const float* __restrict__ bias, const float* __restrict__ pa,
                          float* __restrict__ out, int Nn) {
    int t = threadIdx.x;
    int node = blockIdx.x * 8 + (t >> 5);
    if (node >= Nn) return;
    int f = t & 31;
    int start = cursor[node], end = cursor[node + 1];
    float acc = 0.f;
    for (int j0 = start; j0 < end; j0 += 32) {
        int idx = j0 + f;
        int rf = (idx < end) ? esr[idx] : 0;
        int m = end - j0;
        if (m > 32) m = 32;
        int i = 0;
        for (; i + 4 <= m; i += 4) {
            int r0 = __shfl(rf, i + 0, 32);
            int r1 = __shfl(rf, i + 1, 32);
            int r2 = __shfl(rf, i + 2, 32);
            int r3 = __shfl(rf, i + 3, 32);
            float a0 = xws[(size_t)r0 * F_OUT + f];
            float a1 = xws[(size_t)r1 * F_OUT + f];
            float a2 = xws[(size_t)r2 * F_OUT + f];
            float a3 = xws[(size_t)r3 * F_OUT + f];
            acc += a0 + a1 + a2 + a3;
        }
        for (; i < m; ++i) {
            int r = __shfl(rf, i, 32);
            acc += xws[(size_t)r * F_OUT + f];
        }
    }
    float dc = dis[node];
    float v = (acc + xws[(size_t)node * F_OUT + f]) * dc + bias[f];
    float a = pa[0];
    out[(size_t)node * F_OUT + f] = (v >= 0.f) ? v : a * v;
}

// ---------------- Fallback: atomic scatter path ---------------------------
__global__ void k4_scatter(const int* __restrict__ ei, const float* __restrict__ xws,
                           const float* __restrict__ dis, float* __restrict__ out, int E_) {
    int id = blockIdx.x * blockDim.x + threadIdx.x;
    if (id >= E_ * F_OUT) return;
    int e = id >> 5, f = id & 31;
    int r = ei[e];
    int c = ei[E_ + e];
    atomicAdd(&out[(size_t)c * F_OUT + f], xws[(size_t)r * F_OUT + f] * dis[c]);
}

__global__ void k5_epi(const float* __restrict__ xws, const float* __restrict__ dis,
                       const float* __restrict__ bias, const float* __restrict__ pa,
                       float* __restrict__ out, int Nn) {
    int id = blockIdx.x * blockDim.x + threadIdx.x;
    if (id >= Nn * F_OUT) return;
    int i = id >> 5, f = id & 31;
    float d = dis[i];
    float v = out[id] + xws[id] * d + bias[f];
    float a = pa[0];
    out[id] = (v >= 0.f) ? v : a * v;
}

extern "C" void kernel_launch(void* const* d_in, const int* in_sizes, int n_in,
                              void* d_out, int out_size, void* d_ws, size_t ws_size,
                              hipStream_t stream) {
    const float* x    = (const float*)d_in[0];
    const int*   ei   = (const int*)d_in[1];   // [2,E]: row = ei[0:E], col = ei[E:2E]
    const float* W    = (const float*)d_in[2];
    const float* bias = (const float*)d_in[3];
    const float* pa   = (const float*)d_in[4];
    const float* u    = (const float*)d_in[5];

    int Nn = in_sizes[0] / F_IN;   // 100000
    int E_ = in_sizes[1] / 2;      // 1600000
    float* out = (float*)d_out;

    int NB = (Nn + 127) >> 7;      // buckets of 128 nodes
    int nBG = NB * 8;

    // ws layout (4B words):
    // xw | Wsc | dis | deg | cnt_bg | cursor[N+1] | sgoff[nBG+1] | scur | bsum | staging | esr
    size_t o = 0;
    float*    xw      = (float*)d_ws;        o += (size_t)Nn * F_OUT;
    float*    Wsc     = (float*)d_ws + o;    o += F_OUT * F_IN;
    float*    dis     = (float*)d_ws + o;    o += Nn;
    int*      deg     = (int*)d_ws + o;      o += Nn;
    int*      cnt_bg  = (int*)d_ws + o;      o += nBG;   // adjacent to deg: one memset
    int*      cursor  = (int*)d_ws + o;      o += Nn + 1;
    int*      sgoff   = (int*)d_ws + o;      o += nBG + 1;
    int*      scur    = (int*)d_ws + o;      o += nBG;
    int*      bsum    = (int*)d_ws + o;      o += 256;
    unsigned* staging = (unsigned*)d_ws + o; o += E_;
    int*      esr     = (int*)d_ws + o;      o += E_;
    bool big_ws = ws_size >= o * sizeof(float);

    int nbE = (E_ + 2047) / 2048;   // edge-chunk grid (shared by k2_hist / k_scat1)
    int nbS = (Nn + 1023) / 1024;   // node-scan grid

    if (big_ws) {
        hipMemsetAsync(deg, 0, (size_t)(Nn + nBG) * sizeof(int), stream);
        k0_specnorm<<<1, 128, 0, stream>>>(W, u, Wsc);
        k2_hist<<<nbE, 256, 0, stream>>>(ei + E_, deg, cnt_bg, E_);
        k3_dis<<<(Nn + 255) / 256, 256, 0, stream>>>(deg, dis, Nn);
        k_s1<<<nbS, 256, 0, stream>>>(deg, bsum, Nn);
        k_s2<<<1, 64, 0, stream>>>(bsum, nbS, cursor, Nn);
        k_s3<<<nbS, 256, 0, stream>>>(deg, bsum, cursor, Nn);
        k_sbg<<<1, 256, 0, stream>>>(cnt_bg, sgoff, scur, nBG);
        k1_xw<<<(Nn + 127) / 128, 256, 0, stream>>>(x, Wsc, dis, xw, Nn);
        k_scat1<<<nbE, 256, 0, stream>>>(ei, scur, staging, E_);
        k_sort2<<<NB, 256, 0, stream>>>(staging, sgoff, cursor, esr, Nn);
        k4_gather<<<(Nn + 7) / 8, 256, 0, stream>>>(esr, cursor, xw, dis, bias, pa, out, Nn);
    } else {
        hipMemsetAsync(deg, 0, (size_t)Nn * sizeof(int), stream);
        hipMemsetAsync(d_out, 0, (size_t)Nn * F_OUT * sizeof(float), stream);
        k0_specnorm<<<1, 128, 0, stream>>>(W, u, Wsc);
        k2_hist<<<nbE, 256, 0, stream>>>(ei + E_, deg, cnt_bg, E_);  // cnt_bg unused writes ok? no: guard
        k3_dis<<<(Nn + 255) / 256, 256, 0, stream>>>(deg, dis, Nn);
        k1_xw<<<(Nn + 127) / 128, 256, 0, stream>>>(x, Wsc, dis, xw, Nn);
        int nT4 = E_ * F_OUT;
        k4_scatter<<<(nT4 + 255) / 256, 256, 0, stream>>>(ei, xw, dis, out, E_);
        int nT1 = Nn * F_OUT;
        k5_epi<<<(nT1 + 255) / 256, 256, 0, stream>>>(xw, dis, bias, pa, out, Nn);
    }
}

// Round 4
// 188.583 us; speedup vs baseline: 2.6039x; 2.6039x over previous
//
#include <hip/hip_runtime.h>

#define F_IN 128
#define F_OUT 32
#define PBLK 256   // phase-1 partition blocks
#define BSH 8      // 256 nodes per bucket

// ---------------- K0: spectral norm, write W/sigma to ws ----------------
__global__ void k0_specnorm(const float* __restrict__ W, const float* __restrict__ u,
                            float* __restrict__ Wsc) {
    __shared__ float v[F_IN];
    __shared__ float red[F_IN];
    __shared__ float scal;
    int t = threadIdx.x;  // 0..127
    float acc = 0.f;
    for (int i = 0; i < F_OUT; ++i) acc += W[i * F_IN + t] * u[i];
    v[t] = acc;
    red[t] = acc * acc;
    __syncthreads();
    if (t == 0) {
        float s = 0.f;
        for (int i = 0; i < F_IN; ++i) s += red[i];
        scal = 1.0f / fmaxf(sqrtf(s), 1e-12f);
    }
    __syncthreads();
    v[t] = v[t] * scal;
    __syncthreads();
    if (t < F_OUT) {
        float a2 = 0.f;
        for (int j = 0; j < F_IN; ++j) a2 += W[t * F_IN + j] * v[j];
        red[t] = a2 * a2;
    }
    __syncthreads();
    if (t == 0) {
        float s = 0.f;
        for (int i = 0; i < F_OUT; ++i) s += red[i];
        scal = 1.0f / fmaxf(sqrtf(s), 1e-30f);  // 1/sigma
    }
    __syncthreads();
    float is = scal;
    for (int i = 0; i < F_OUT; ++i)
        Wsc[i * F_IN + t] = W[i * F_IN + t] * is;
}

// ---------------- K1: xws = (x @ Wsc^T) * dis[row], LDS-tiled -----------
__global__ __launch_bounds__(256) void k1_xw(const float* __restrict__ x,
                                             const float* __restrict__ Wsc,
                                             const float* __restrict__ dis,
                                             float* __restrict__ xw, int Nn) {
    __shared__ float xs[128 * 65];
    __shared__ float wt[128 * 32];
    int t = threadIdx.x;
    int rbase = blockIdx.x * 128;

    {   // stage W transposed
        int f = t >> 3;
        int kb = 16 * (t & 7);
        const float4* wrow = (const float4*)(Wsc + (size_t)f * F_IN + kb);
#pragma unroll
        for (int j = 0; j < 4; ++j) {
            float4 w = wrow[j];
            int k = kb + 4 * j;
            wt[(k + 0) * 32 + f] = w.x;
            wt[(k + 1) * 32 + f] = w.y;
            wt[(k + 2) * 32 + f] = w.z;
            wt[(k + 3) * 32 + f] = w.w;
        }
    }

    int r0 = (t >> 3) * 4;
    int f0 = (t & 7) * 4;
    float4 acc0 = {0, 0, 0, 0}, acc1 = {0, 0, 0, 0};
    float4 acc2 = {0, 0, 0, 0}, acc3 = {0, 0, 0, 0};
    const float4* wt4 = (const float4*)wt;
    int fq = f0 >> 2;

    for (int kc = 0; kc < 2; ++kc) {
        __syncthreads();
        {
            int rr = t >> 4;
            int k0 = 4 * (t & 15);
#pragma unroll
            for (int p = 0; p < 8; ++p) {
                int r = p * 16 + rr;
                int grow = rbase + r;
                if (grow >= Nn) grow = Nn - 1;
                float4 v = *(const float4*)(x + (size_t)grow * F_IN + kc * 64 + k0);
                xs[r * 65 + k0 + 0] = v.x;
                xs[r * 65 + k0 + 1] = v.y;
                xs[r * 65 + k0 + 2] = v.z;
                xs[r * 65 + k0 + 3] = v.w;
            }
        }
        __syncthreads();
#pragma unroll 4
        for (int kk = 0; kk < 64; ++kk) {
            int k = kc * 64 + kk;
            float4 w = wt4[k * 8 + fq];
            float x0 = xs[(r0 + 0) * 65 + kk];
            float x1 = xs[(r0 + 1) * 65 + kk];
            float x2 = xs[(r0 + 2) * 65 + kk];
            float x3 = xs[(r0 + 3) * 65 + kk];
            acc0.x += x0 * w.x; acc0.y += x0 * w.y; acc0.z += x0 * w.z; acc0.w += x0 * w.w;
            acc1.x += x1 * w.x; acc1.y += x1 * w.y; acc1.z += x1 * w.z; acc1.w += x1 * w.w;
            acc2.x += x2 * w.x; acc2.y += x2 * w.y; acc2.z += x2 * w.z; acc2.w += x2 * w.w;
            acc3.x += x3 * w.x; acc3.y += x3 * w.y; acc3.z += x3 * w.z; acc3.w += x3 * w.w;
        }
    }
    int g0 = rbase + r0;
#pragma unroll
    for (int q = 0; q < 4; ++q) {
        int g = g0 + q;
        if (g < Nn) {
            float d = dis[g];
            float4 a = (q == 0) ? acc0 : (q == 1) ? acc1 : (q == 2) ? acc2 : acc3;
            a.x *= d; a.y *= d; a.z *= d; a.w *= d;
            *(float4*)(xw + (size_t)g * F_OUT + f0) = a;
        }
    }
}

// ---- k_hist: per-block LDS-private bucket histogram -> M[b][p] ----------
__global__ void k_hist(const int* __restrict__ col, int* __restrict__ M,
                       int E_, int NB) {
    __shared__ int h[512];
    int p = blockIdx.x, t = threadIdx.x;
    for (int b = t; b < NB; b += 256) h[b] = 0;
    __syncthreads();
    int epb = (E_ + PBLK - 1) / PBLK;
    int e0 = p * epb, e1 = min(e0 + epb, E_);
    for (int e = e0 + t; e < e1; e += 256)
        atomicAdd(&h[col[e] >> BSH], 1);
    __syncthreads();
    for (int b = t; b < NB; b += 256) M[b * PBLK + p] = h[b];
}

// ---- k_scanA: exclusive scan of each M row (over blocks) + row total -----
__global__ void k_scanA(int* __restrict__ M, int* __restrict__ total, int NB) {
    __shared__ int sd[256];
    int b = blockIdx.x, t = threadIdx.x;
    int v = M[b * PBLK + t];
    sd[t] = v;
    __syncthreads();
    for (int o = 1; o < 256; o <<= 1) {
        int u = (t >= o) ? sd[t - o] : 0;
        __syncthreads();
        sd[t] += u;
        __syncthreads();
    }
    M[b * PBLK + t] = sd[t] - v;  // exclusive within row
    if (t == 255) total[b] = sd[255];
}

// ---- k_scanB: exclusive scan of bucket totals -> base[NB+1] --------------
__global__ void k_scanB(const int* __restrict__ total, int* __restrict__ base, int NB) {
    __shared__ int sd[512];
    int t = threadIdx.x;
    int v = (t < NB) ? total[t] : 0;
    sd[t] = v;
    __syncthreads();
    for (int o = 1; o < 512; o <<= 1) {
        int u = (t >= o) ? sd[t - o] : 0;
        __syncthreads();
        sd[t] += u;
        __syncthreads();
    }
    if (t < NB) base[t] = sd[t] - v;
    if (t == NB - 1) base[NB] = sd[t];  // == E
}

// ---- k_scat1: partition scatter, LDS cursors, NO global atomics ----------
__global__ void k_scat1(const int* __restrict__ ei, const int* __restrict__ M,
                        const int* __restrict__ base, unsigned* __restrict__ staging,
                        int E_, int NB) {
    __shared__ int cur[512];
    int p = blockIdx.x, t = threadIdx.x;
    for (int b = t; b < NB; b += 256) cur[b] = base[b] + M[b * PBLK + p];
    __syncthreads();
    int epb = (E_ + PBLK - 1) / PBLK;
    int e0 = p * epb, e1 = min(e0 + epb, E_);
    for (int e = e0 + t; e < e1; e += 256) {
        int c = ei[E_ + e];
        int r = ei[e];
        int b = c >> BSH;
        int pos = atomicAdd(&cur[b], 1);  // LDS atomic (block-private)
        staging[pos] = ((unsigned)r << BSH) | (unsigned)(c & 255);
    }
}

// ---- k_sort2: per-bucket sort + deg/dis/cursor, NO global atomics --------
__global__ void k_sort2(const unsigned* __restrict__ staging, const int* __restrict__ base,
                        int* __restrict__ esr, float* __restrict__ dis,
                        int* __restrict__ cursor, int Nn, int E_, int NB) {
    __shared__ int hist[256];
    __shared__ int sd[256];
    __shared__ int lcur[256];
    int b = blockIdx.x, t = threadIdx.x;
    int nb0 = b << BSH;
    int nc = min(256, Nn - nb0);
    hist[t] = 0;
    __syncthreads();
    int s0 = base[b], s1 = base[b + 1];
    for (int j = s0 + t; j < s1; j += 256)
        atomicAdd(&hist[staging[j] & 255], 1);  // LDS atomic
    __syncthreads();
    int h = hist[t];
    if (t < nc) dis[nb0 + t] = rsqrtf((float)h + 1.0f);
    sd[t] = h;
    __syncthreads();
    for (int o = 1; o < 256; o <<= 1) {
        int u = (t >= o) ? sd[t - o] : 0;
        __syncthreads();
        sd[t] += u;
        __syncthreads();
    }
    int excl = sd[t] - h;
    if (t < nc) cursor[nb0 + t] = s0 + excl;
    if (b == NB - 1 && t == 0) cursor[Nn] = E_;
    lcur[t] = s0 + excl;
    __syncthreads();
    for (int j = s0 + t; j < s1; j += 256) {
        unsigned v = staging[j];
        int p = atomicAdd(&lcur[v & 255], 1);  // LDS atomic
        esr[p] = (int)(v >> BSH);
    }
}

// ---- K4g: per-node gather + epilogue (chunked shfl broadcast) ------------
__global__ void k4_gather(const int* __restrict__ esr, const int* __restrict__ cursor,
                          const float* __restrict__ xws, const float* __restrict__ dis,
                          const float* __restrict__ bias, const float* __restrict__ pa,
                          float* __restrict__ out, int Nn) {
    int t = threadIdx.x;
    int node = blockIdx.x * 8 + (t >> 5);
    if (node >= Nn) return;
    int f = t & 31;
    int start = cursor[node], end = cursor[node + 1];
    float acc = 0.f;
    for (int j0 = start; j0 < end; j0 += 32) {
        int idx = j0 + f;
        int rf = (idx < end) ? esr[idx] : 0;
        int m = end - j0;
        if (m > 32) m = 32;
        int i = 0;
        for (; i + 4 <= m; i += 4) {
            int r0 = __shfl(rf, i + 0, 32);
            int r1 = __shfl(rf, i + 1, 32);
            int r2 = __shfl(rf, i + 2, 32);
            int r3 = __shfl(rf, i + 3, 32);
            float a0 = xws[(size_t)r0 * F_OUT + f];
            float a1 = xws[(size_t)r1 * F_OUT + f];
            float a2 = xws[(size_t)r2 * F_OUT + f];
            float a3 = xws[(size_t)r3 * F_OUT + f];
            acc += a0 + a1 + a2 + a3;
        }
        for (; i < m; ++i) {
            int r = __shfl(rf, i, 32);
            acc += xws[(size_t)r * F_OUT + f];
        }
    }
    float dc = dis[node];
    float v = (acc + xws[(size_t)node * F_OUT + f]) * dc + bias[f];
    float a = pa[0];
    out[(size_t)node * F_OUT + f] = (v >= 0.f) ? v : a * v;
}

// ---------------- Fallback path (small ws): atomic scatter ----------------
__global__ void k2_deg(const int* __restrict__ col, int* __restrict__ cnt, int E_) {
    int e = blockIdx.x * blockDim.x + threadIdx.x;
    if (e < E_) atomicAdd(&cnt[col[e]], 1);
}

__global__ void k3_dis(const int* __restrict__ cnt, float* __restrict__ dis, int Nn) {
    int i = blockIdx.x * blockDim.x + threadIdx.x;
    if (i < Nn) dis[i] = rsqrtf((float)cnt[i] + 1.0f);
}

__global__ void k4_scatter(const int* __restrict__ ei, const float* __restrict__ xws,
                           const float* __restrict__ dis, float* __restrict__ out, int E_) {
    int id = blockIdx.x * blockDim.x + threadIdx.x;
    if (id >= E_ * F_OUT) return;
    int e = id >> 5, f = id & 31;
    int r = ei[e];
    int c = ei[E_ + e];
    atomicAdd(&out[(size_t)c * F_OUT + f], xws[(size_t)r * F_OUT + f] * dis[c]);
}

__global__ void k5_epi(const float* __restrict__ xws, const float* __restrict__ dis,
                       const float* __restrict__ bias, const float* __restrict__ pa,
                       float* __restrict__ out, int Nn) {
    int id = blockIdx.x * blockDim.x + threadIdx.x;
    if (id >= Nn * F_OUT) return;
    int i = id >> 5, f = id & 31;
    float d = dis[i];
    float v = out[id] + xws[id] * d + bias[f];
    float a = pa[0];
    out[id] = (v >= 0.f) ? v : a * v;
}

extern "C" void kernel_launch(void* const* d_in, const int* in_sizes, int n_in,
                              void* d_out, int out_size, void* d_ws, size_t ws_size,
                              hipStream_t stream) {
    const float* x    = (const float*)d_in[0];
    const int*   ei   = (const int*)d_in[1];   // [2,E]: row = ei[0:E], col = ei[E:2E]
    const float* W    = (const float*)d_in[2];
    const float* bias = (const float*)d_in[3];
    const float* pa   = (const float*)d_in[4];
    const float* u    = (const float*)d_in[5];

    int Nn = in_sizes[0] / F_IN;   // 100000
    int E_ = in_sizes[1] / 2;      // 1600000
    float* out = (float*)d_out;

    int NB = (Nn + 255) >> BSH;    // buckets of 256 nodes (<= 512 assumed)

    // ws layout (4B words):
    // xw [N*32] | Wsc | dis [N] | cursor [N+1] | M [NB*PBLK] | total [NB] |
    // base [NB+1] | staging [E] | esr [E]
    size_t o = 0;
    float*    xw      = (float*)d_ws;        o += (size_t)Nn * F_OUT;
    float*    Wsc     = (float*)d_ws + o;    o += F_OUT * F_IN;
    float*    dis     = (float*)d_ws + o;    o += Nn;
    int*      cursor  = (int*)d_ws + o;      o += Nn + 1;
    int*      M       = (int*)d_ws + o;      o += (size_t)NB * PBLK;
    int*      total   = (int*)d_ws + o;      o += NB;
    int*      base    = (int*)d_ws + o;      o += NB + 1;
    unsigned* staging = (unsigned*)d_ws + o; o += E_;
    int*      esr     = (int*)d_ws + o;      o += E_;
    bool big_ws = (ws_size >= o * sizeof(float)) && (NB <= 512);

    if (big_ws) {
        k0_specnorm<<<1, 128, 0, stream>>>(W, u, Wsc);
        k_hist<<<PBLK, 256, 0, stream>>>(ei + E_, M, E_, NB);
        k_scanA<<<NB, 256, 0, stream>>>(M, total, NB);
        k_scanB<<<1, 512, 0, stream>>>(total, base, NB);
        k_scat1<<<PBLK, 256, 0, stream>>>(ei, M, base, staging, E_, NB);
        k_sort2<<<NB, 256, 0, stream>>>(staging, base, esr, dis, cursor, Nn, E_, NB);
        k1_xw<<<(Nn + 127) / 128, 256, 0, stream>>>(x, Wsc, dis, xw, Nn);
        k4_gather<<<(Nn + 7) / 8, 256, 0, stream>>>(esr, cursor, xw, dis, bias, pa, out, Nn);
    } else {
        int* deg = cursor;  // reuse
        hipMemsetAsync(deg, 0, (size_t)Nn * sizeof(int), stream);
        hipMemsetAsync(d_out, 0, (size_t)Nn * F_OUT * sizeof(float), stream);
        k0_specnorm<<<1, 128, 0, stream>>>(W, u, Wsc);
        k2_deg<<<(E_ + 255) / 256, 256, 0, stream>>>(ei + E_, deg, E_);
        k3_dis<<<(Nn + 255) / 256, 256, 0, stream>>>(deg, dis, Nn);
        k1_xw<<<(Nn + 127) / 128, 256, 0, stream>>>(x, Wsc, dis, xw, Nn);
        int nT4 = E_ * F_OUT;
        k4_scatter<<<(nT4 + 255) / 256, 256, 0, stream>>>(ei, xw, dis, out, E_);
        int nT1 = Nn * F_OUT;
        k5_epi<<<(nT1 + 255) / 256, 256, 0, stream>>>(xw, dis, bias, pa, out, Nn);
    }
}

// Round 5
// 182.450 us; speedup vs baseline: 2.6915x; 1.0336x over previous
//
#include <hip/hip_runtime.h>
#include <hip/hip_fp16.h>

#define F_IN 128
#define F_OUT 32
#define PBLK 256   // phase-1 partition blocks
#define BSH 8      // 256 nodes per bucket

// ---------------- K0: spectral norm, write W/sigma to ws ----------------
__global__ void k0_specnorm(const float* __restrict__ W, const float* __restrict__ u,
                            float* __restrict__ Wsc) {
    __shared__ float v[F_IN];
    __shared__ float red[F_IN];
    __shared__ float scal;
    int t = threadIdx.x;  // 0..127
    float acc = 0.f;
    for (int i = 0; i < F_OUT; ++i) acc += W[i * F_IN + t] * u[i];
    v[t] = acc;
    red[t] = acc * acc;
    __syncthreads();
    if (t == 0) {
        float s = 0.f;
        for (int i = 0; i < F_IN; ++i) s += red[i];
        scal = 1.0f / fmaxf(sqrtf(s), 1e-12f);
    }
    __syncthreads();
    v[t] = v[t] * scal;
    __syncthreads();
    if (t < F_OUT) {
        float a2 = 0.f;
        for (int j = 0; j < F_IN; ++j) a2 += W[t * F_IN + j] * v[j];
        red[t] = a2 * a2;
    }
    __syncthreads();
    if (t == 0) {
        float s = 0.f;
        for (int i = 0; i < F_OUT; ++i) s += red[i];
        scal = 1.0f / fmaxf(sqrtf(s), 1e-30f);  // 1/sigma
    }
    __syncthreads();
    float is = scal;
    for (int i = 0; i < F_OUT; ++i)
        Wsc[i * F_IN + t] = W[i * F_IN + t] * is;
}

// ---------------- K1: xws(f16) = (x @ Wsc^T) * dis[row], LDS-tiled ------
__global__ __launch_bounds__(256) void k1_xw(const float* __restrict__ x,
                                             const float* __restrict__ Wsc,
                                             const float* __restrict__ dis,
                                             __half* __restrict__ xwh, int Nn) {
    __shared__ float xs[128 * 65];
    __shared__ float wt[128 * 32];
    int t = threadIdx.x;
    int rbase = blockIdx.x * 128;

    {   // stage W transposed
        int f = t >> 3;
        int kb = 16 * (t & 7);
        const float4* wrow = (const float4*)(Wsc + (size_t)f * F_IN + kb);
#pragma unroll
        for (int j = 0; j < 4; ++j) {
            float4 w = wrow[j];
            int k = kb + 4 * j;
            wt[(k + 0) * 32 + f] = w.x;
            wt[(k + 1) * 32 + f] = w.y;
            wt[(k + 2) * 32 + f] = w.z;
            wt[(k + 3) * 32 + f] = w.w;
        }
    }

    int r0 = (t >> 3) * 4;
    int f0 = (t & 7) * 4;
    float4 acc0 = {0, 0, 0, 0}, acc1 = {0, 0, 0, 0};
    float4 acc2 = {0, 0, 0, 0}, acc3 = {0, 0, 0, 0};
    const float4* wt4 = (const float4*)wt;
    int fq = f0 >> 2;

    for (int kc = 0; kc < 2; ++kc) {
        __syncthreads();
        {
            int rr = t >> 4;
            int k0 = 4 * (t & 15);
#pragma unroll
            for (int p = 0; p < 8; ++p) {
                int r = p * 16 + rr;
                int grow = rbase + r;
                if (grow >= Nn) grow = Nn - 1;
                float4 v = *(const float4*)(x + (size_t)grow * F_IN + kc * 64 + k0);
                xs[r * 65 + k0 + 0] = v.x;
                xs[r * 65 + k0 + 1] = v.y;
                xs[r * 65 + k0 + 2] = v.z;
                xs[r * 65 + k0 + 3] = v.w;
            }
        }
        __syncthreads();
#pragma unroll 4
        for (int kk = 0; kk < 64; ++kk) {
            int k = kc * 64 + kk;
            float4 w = wt4[k * 8 + fq];
            float x0 = xs[(r0 + 0) * 65 + kk];
            float x1 = xs[(r0 + 1) * 65 + kk];
            float x2 = xs[(r0 + 2) * 65 + kk];
            float x3 = xs[(r0 + 3) * 65 + kk];
            acc0.x += x0 * w.x; acc0.y += x0 * w.y; acc0.z += x0 * w.z; acc0.w += x0 * w.w;
            acc1.x += x1 * w.x; acc1.y += x1 * w.y; acc1.z += x1 * w.z; acc1.w += x1 * w.w;
            acc2.x += x2 * w.x; acc2.y += x2 * w.y; acc2.z += x2 * w.z; acc2.w += x2 * w.w;
            acc3.x += x3 * w.x; acc3.y += x3 * w.y; acc3.z += x3 * w.z; acc3.w += x3 * w.w;
        }
    }
    int g0 = rbase + r0;
#pragma unroll
    for (int q = 0; q < 4; ++q) {
        int g = g0 + q;
        if (g < Nn) {
            float d = dis[g];
            float4 a = (q == 0) ? acc0 : (q == 1) ? acc1 : (q == 2) ? acc2 : acc3;
            ushort4 s;
            s.x = __half_as_ushort(__float2half(a.x * d));
            s.y = __half_as_ushort(__float2half(a.y * d));
            s.z = __half_as_ushort(__float2half(a.z * d));
            s.w = __half_as_ushort(__float2half(a.w * d));
            *(ushort4*)(xwh + (size_t)g * F_OUT + f0) = s;
        }
    }
}

// ---- k_hist: per-block LDS-private bucket histogram -> M[b][p] ----------
__global__ void k_hist(const int* __restrict__ col, int* __restrict__ M,
                       int E_, int NB) {
    __shared__ int h[512];
    int p = blockIdx.x, t = threadIdx.x;
    for (int b = t; b < NB; b += 256) h[b] = 0;
    __syncthreads();
    int epb = (E_ + PBLK - 1) / PBLK;
    int e0 = p * epb, e1 = min(e0 + epb, E_);
    for (int e = e0 + t; e < e1; e += 256)
        atomicAdd(&h[col[e] >> BSH], 1);
    __syncthreads();
    for (int b = t; b < NB; b += 256) M[b * PBLK + p] = h[b];
}

// ---- k_scanA: exclusive scan of each M row (over blocks) + row total -----
__global__ void k_scanA(int* __restrict__ M, int* __restrict__ total, int NB) {
    __shared__ int sd[256];
    int b = blockIdx.x, t = threadIdx.x;
    int v = M[b * PBLK + t];
    sd[t] = v;
    __syncthreads();
    for (int o = 1; o < 256; o <<= 1) {
        int u = (t >= o) ? sd[t - o] : 0;
        __syncthreads();
        sd[t] += u;
        __syncthreads();
    }
    M[b * PBLK + t] = sd[t] - v;  // exclusive within row
    if (t == 255) total[b] = sd[255];
}

// ---- k_scanB: exclusive scan of bucket totals -> base[NB+1] --------------
__global__ void k_scanB(const int* __restrict__ total, int* __restrict__ base, int NB) {
    __shared__ int sd[512];
    int t = threadIdx.x;
    int v = (t < NB) ? total[t] : 0;
    sd[t] = v;
    __syncthreads();
    for (int o = 1; o < 512; o <<= 1) {
        int u = (t >= o) ? sd[t - o] : 0;
        __syncthreads();
        sd[t] += u;
        __syncthreads();
    }
    if (t < NB) base[t] = sd[t] - v;
    if (t == NB - 1) base[NB] = sd[t];  // == E
}

// ---- k_scat1: partition scatter, LDS cursors, NO global atomics ----------
__global__ void k_scat1(const int* __restrict__ ei, const int* __restrict__ M,
                        const int* __restrict__ base, unsigned* __restrict__ staging,
                        int E_, int NB) {
    __shared__ int cur[512];
    int p = blockIdx.x, t = threadIdx.x;
    for (int b = t; b < NB; b += 256) cur[b] = base[b] + M[b * PBLK + p];
    __syncthreads();
    int epb = (E_ + PBLK - 1) / PBLK;
    int e0 = p * epb, e1 = min(e0 + epb, E_);
    for (int e = e0 + t; e < e1; e += 256) {
        int c = ei[E_ + e];
        int r = ei[e];
        int b = c >> BSH;
        int pos = atomicAdd(&cur[b], 1);  // LDS atomic (block-private)
        staging[pos] = ((unsigned)r << BSH) | (unsigned)(c & 255);
    }
}

// ---- k_sort2: per-bucket sort + deg/dis/cursor, NO global atomics --------
__global__ void k_sort2(const unsigned* __restrict__ staging, const int* __restrict__ base,
                        int* __restrict__ esr, float* __restrict__ dis,
                        int* __restrict__ cursor, int Nn, int E_, int NB) {
    __shared__ int hist[256];
    __shared__ int sd[256];
    __shared__ int lcur[256];
    int b = blockIdx.x, t = threadIdx.x;
    int nb0 = b << BSH;
    int nc = min(256, Nn - nb0);
    hist[t] = 0;
    __syncthreads();
    int s0 = base[b], s1 = base[b + 1];
    for (int j = s0 + t; j < s1; j += 256)
        atomicAdd(&hist[staging[j] & 255], 1);  // LDS atomic
    __syncthreads();
    int h = hist[t];
    if (t < nc) dis[nb0 + t] = rsqrtf((float)h + 1.0f);
    sd[t] = h;
    __syncthreads();
    for (int o = 1; o < 256; o <<= 1) {
        int u = (t >= o) ? sd[t - o] : 0;
        __syncthreads();
        sd[t] += u;
        __syncthreads();
    }
    int excl = sd[t] - h;
    if (t < nc) cursor[nb0 + t] = s0 + excl;
    if (b == NB - 1 && t == 0) cursor[Nn] = E_;
    lcur[t] = s0 + excl;
    __syncthreads();
    for (int j = s0 + t; j < s1; j += 256) {
        unsigned v = staging[j];
        int p = atomicAdd(&lcur[v & 255], 1);  // LDS atomic
        esr[p] = (int)(v >> BSH);
    }
}

// ---- K4g: per-node gather, 16-lane groups, half2 loads -------------------
__global__ void k4_gather(const int* __restrict__ esr, const int* __restrict__ cursor,
                          const __half* __restrict__ xws, const float* __restrict__ dis,
                          const float* __restrict__ bias, const float* __restrict__ pa,
                          float* __restrict__ out, int Nn) {
    int t = threadIdx.x;
    int node = blockIdx.x * 16 + (t >> 4);
    if (node >= Nn) return;
    int f2 = t & 15;  // feature pair: features 2*f2, 2*f2+1
    int start = cursor[node], end = cursor[node + 1];
    float accx = 0.f, accy = 0.f;
    for (int j0 = start; j0 < end; j0 += 16) {
        int idx = j0 + f2;
        int rf = (idx < end) ? esr[idx] : 0;
        int m = end - j0;
        if (m > 16) m = 16;
        int i = 0;
        for (; i + 4 <= m; i += 4) {
            int r0 = __shfl(rf, i + 0, 16);
            int r1 = __shfl(rf, i + 1, 16);
            int r2 = __shfl(rf, i + 2, 16);
            int r3 = __shfl(rf, i + 3, 16);
            float2 a0 = __half22float2(*((const __half2*)(xws + (size_t)r0 * F_OUT) + f2));
            float2 a1 = __half22float2(*((const __half2*)(xws + (size_t)r1 * F_OUT) + f2));
            float2 a2 = __half22float2(*((const __half2*)(xws + (size_t)r2 * F_OUT) + f2));
            float2 a3 = __half22float2(*((const __half2*)(xws + (size_t)r3 * F_OUT) + f2));
            accx += a0.x + a1.x + a2.x + a3.x;
            accy += a0.y + a1.y + a2.y + a3.y;
        }
        for (; i < m; ++i) {
            int r = __shfl(rf, i, 16);
            float2 a = __half22float2(*((const __half2*)(xws + (size_t)r * F_OUT) + f2));
            accx += a.x;
            accy += a.y;
        }
    }
    float dc = dis[node];
    float2 self = __half22float2(*((const __half2*)(xws + (size_t)node * F_OUT) + f2));
    float2 bi = *((const float2*)bias + f2);
    float a = pa[0];
    float vx = (accx + self.x) * dc + bi.x;
    float vy = (accy + self.y) * dc + bi.y;
    float2 o;
    o.x = (vx >= 0.f) ? vx : a * vx;
    o.y = (vy >= 0.f) ? vy : a * vy;
    *((float2*)(out + (size_t)node * F_OUT) + f2) = o;
}

// ---------------- Fallback path (small ws): atomic scatter, fp32 ----------
__global__ void k1_xw_f32(const float* __restrict__ x, const float* __restrict__ Wsc,
                          const float* __restrict__ dis, float* __restrict__ xw, int Nn) {
    int id = blockIdx.x * blockDim.x + threadIdx.x;
    if (id >= Nn * F_OUT) return;
    int r = id >> 5, f = id & 31;
    const float4* x4 = (const float4*)(x + (size_t)r * F_IN);
    const float4* w4 = (const float4*)(Wsc + (size_t)f * F_IN);
    float acc = 0.f;
#pragma unroll
    for (int k = 0; k < F_IN / 4; ++k) {
        float4 a = x4[k];
        float4 b = w4[k];
        acc += a.x * b.x + a.y * b.y + a.z * b.z + a.w * b.w;
    }
    xw[id] = acc * dis[r];
}

__global__ void k2_deg(const int* __restrict__ col, int* __restrict__ cnt, int E_) {
    int e = blockIdx.x * blockDim.x + threadIdx.x;
    if (e < E_) atomicAdd(&cnt[col[e]], 1);
}

__global__ void k3_dis(const int* __restrict__ cnt, float* __restrict__ dis, int Nn) {
    int i = blockIdx.x * blockDim.x + threadIdx.x;
    if (i < Nn) dis[i] = rsqrtf((float)cnt[i] + 1.0f);
}

__global__ void k4_scatter(const int* __restrict__ ei, const float* __restrict__ xws,
                           const float* __restrict__ dis, float* __restrict__ out, int E_) {
    int id = blockIdx.x * blockDim.x + threadIdx.x;
    if (id >= E_ * F_OUT) return;
    int e = id >> 5, f = id & 31;
    int r = ei[e];
    int c = ei[E_ + e];
    atomicAdd(&out[(size_t)c * F_OUT + f], xws[(size_t)r * F_OUT + f] * dis[c]);
}

__global__ void k5_epi(const float* __restrict__ xws, const float* __restrict__ dis,
                       const float* __restrict__ bias, const float* __restrict__ pa,
                       float* __restrict__ out, int Nn) {
    int id = blockIdx.x * blockDim.x + threadIdx.x;
    if (id >= Nn * F_OUT) return;
    int i = id >> 5, f = id & 31;
    float d = dis[i];
    float v = out[id] + xws[id] * d + bias[f];
    float a = pa[0];
    out[id] = (v >= 0.f) ? v : a * v;
}

extern "C" void kernel_launch(void* const* d_in, const int* in_sizes, int n_in,
                              void* d_out, int out_size, void* d_ws, size_t ws_size,
                              hipStream_t stream) {
    const float* x    = (const float*)d_in[0];
    const int*   ei   = (const int*)d_in[1];   // [2,E]: row = ei[0:E], col = ei[E:2E]
    const float* W    = (const float*)d_in[2];
    const float* bias = (const float*)d_in[3];
    const float* pa   = (const float*)d_in[4];
    const float* u    = (const float*)d_in[5];

    int Nn = in_sizes[0] / F_IN;   // 100000
    int E_ = in_sizes[1] / 2;      // 1600000
    float* out = (float*)d_out;

    int NB = (Nn + 255) >> BSH;    // buckets of 256 nodes (<= 512 assumed)

    // ws layout (4B words):
    // xwh [N*32 halves = N*16 words] | Wsc | dis [N] | cursor [N+1] |
    // M [NB*PBLK] | total [NB] | base [NB+1] | staging [E] | esr [E]
    size_t o = 0;
    __half*   xwh     = (__half*)d_ws;       o += (size_t)Nn * (F_OUT / 2);
    float*    Wsc     = (float*)d_ws + o;    o += F_OUT * F_IN;
    float*    dis     = (float*)d_ws + o;    o += Nn;
    int*      cursor  = (int*)d_ws + o;      o += Nn + 1;
    int*      M       = (int*)d_ws + o;      o += (size_t)NB * PBLK;
    int*      total   = (int*)d_ws + o;      o += NB;
    int*      base    = (int*)d_ws + o;      o += NB + 1;
    unsigned* staging = (unsigned*)d_ws + o; o += E_;
    int*      esr     = (int*)d_ws + o;      o += E_;
    bool big_ws = (ws_size >= o * sizeof(float)) && (NB <= 512);

    if (big_ws) {
        k0_specnorm<<<1, 128, 0, stream>>>(W, u, Wsc);
        k_hist<<<PBLK, 256, 0, stream>>>(ei + E_, M, E_, NB);
        k_scanA<<<NB, 256, 0, stream>>>(M, total, NB);
        k_scanB<<<1, 512, 0, stream>>>(total, base, NB);
        k_scat1<<<PBLK, 256, 0, stream>>>(ei, M, base, staging, E_, NB);
        k_sort2<<<NB, 256, 0, stream>>>(staging, base, esr, dis, cursor, Nn, E_, NB);
        k1_xw<<<(Nn + 127) / 128, 256, 0, stream>>>(x, Wsc, dis, xwh, Nn);
        k4_gather<<<(Nn + 15) / 16, 256, 0, stream>>>(esr, cursor, xwh, dis, bias, pa, out, Nn);
    } else {
        // fp32 fallback: reuse ws as fp32 xw | Wsc | dis | deg
        size_t o2 = 0;
        float* xw2  = (float*)d_ws;       o2 += (size_t)Nn * F_OUT;
        float* Wsc2 = (float*)d_ws + o2;  o2 += F_OUT * F_IN;
        float* dis2 = (float*)d_ws + o2;  o2 += Nn;
        int*   deg2 = (int*)d_ws + o2;    o2 += Nn;
        hipMemsetAsync(deg2, 0, (size_t)Nn * sizeof(int), stream);
        hipMemsetAsync(d_out, 0, (size_t)Nn * F_OUT * sizeof(float), stream);
        k0_specnorm<<<1, 128, 0, stream>>>(W, u, Wsc2);
        k2_deg<<<(E_ + 255) / 256, 256, 0, stream>>>(ei + E_, deg2, E_);
        k3_dis<<<(Nn + 255) / 256, 256, 0, stream>>>(deg2, dis2, Nn);
        int nT1 = Nn * F_OUT;
        k1_xw_f32<<<(nT1 + 255) / 256, 256, 0, stream>>>(x, Wsc2, dis2, xw2, Nn);
        int nT4 = E_ * F_OUT;
        k4_scatter<<<(nT4 + 255) / 256, 256, 0, stream>>>(ei, xw2, dis2, out, E_);
        k5_epi<<<(nT1 + 255) / 256, 256, 0, stream>>>(xw2, dis2, bias, pa, out, Nn);
    }
}